// Round 7
// baseline (919.402 us; speedup 1.0000x reference)
//
#include <hip/hip_runtime.h>

// Problem geometry
// x: (8,96,256,256) fp32. BC = 768 images of 256x256.
// Out 0: xlo (768,128,128); Out 1: xhi_dir (768,4,128,128).
// Scratch: SHEARED xhi (xs) in d_ws.
//
// R7: (a) k34 quarter-tiles: 36.9KB LDS -> 4 independent blocks/CU so
// Stage-A memory overlaps Stage-B VALU (R6 had 1 block/CU, 260us serial).
// (b) K2: 2x4 outputs/thread (shared 4x6 xlo window), grid halved.
// (c) K1: dense b128 x loads (100% transaction density vs 50% float2).

#define BC 768

// ---------------------------------------------------------------------------
// K1: xlo[r,c] = sum_{i,j<5} h[i]h[j] x[(2r+i-2)%256, (2c+j-2)%256]
// 2x2 outputs/thread; per row 2 b128 + 1 b32, all lane-dense.
// ---------------------------------------------------------------------------
__global__ __launch_bounds__(256) void k1_lowpass(
    const float* __restrict__ x, const float* __restrict__ h,
    float* __restrict__ xlo)
{
    int t = threadIdx.x;
    int tid = blockIdx.x * 256 + t;
    int cb = tid & 63;          // output cols 2cb, 2cb+1
    int rb = (tid >> 6) & 63;   // output rows 2rb, 2rb+1
    int bc = tid >> 12;
    const float* xb = x + (size_t)bc * 65536;

    int c0 = (4 * cb - 4) & 255;       // X[m] = col c0+m
    int c4 = (c0 + 4) & 255;
    int c8 = (c0 + 8) & 255;

    float a00 = 0.f, a01 = 0.f, a10 = 0.f, a11 = 0.f;
    #pragma unroll
    for (int pr = 0; pr < 7; ++pr) {
        int row = (4 * rb - 2 + pr) & 255;
        const float* xr = xb + row * 256;
        float4 v0 = *(const float4*)(xr + c0);
        float4 v1 = *(const float4*)(xr + c4);
        float X8 = xr[c8];
        // s0: cols 4cb-2..4cb+2 (m=2..6); s1: cols 4cb..4cb+4 (m=4..8)
        float s0 = h[0]*v0.z + h[1]*v0.w + h[2]*v1.x + h[3]*v1.y + h[4]*v1.z;
        float s1 = h[0]*v1.x + h[1]*v1.y + h[2]*v1.z + h[3]*v1.w + h[4]*X8;
        if (pr <= 4) { a00 += h[pr] * s0;     a01 += h[pr] * s1; }
        if (pr >= 2) { a10 += h[pr - 2] * s0; a11 += h[pr - 2] * s1; }
    }
    size_t ob = (size_t)bc * 16384 + (size_t)(2 * rb) * 128 + 2 * cb;
    *(float2*)(xlo + ob)       = make_float2(a00, a01);
    *(float2*)(xlo + ob + 128) = make_float2(a10, a11);
}

// ---------------------------------------------------------------------------
// K2: xhi[h,w] = x[h,w] - sum g[i]g[j] up[(h+i-3)%256,(w+j-3)%256]
// 2 rows x 4 cols per thread: shared 4-row x 6-col xlo window (3 b64/row).
// Sheared store: xs[row][(col-row+2)&255] = xhi[row][col].
// ---------------------------------------------------------------------------
__global__ __launch_bounds__(256) void k2_highpass(
    const float* __restrict__ x, const float* __restrict__ g,
    const float* __restrict__ xlo, float* __restrict__ xs)
{
    int t = threadIdx.x;
    int tid = blockIdx.x * 256 + t;
    int cw = tid & 63;           // w = 4cw..4cw+3
    int rh = (tid >> 6) & 127;   // h = 2rh, 2rh+1
    int bc = tid >> 13;
    const float* lob = xlo + (size_t)bc * 16384;

    int ri[4] = { (rh - 1) & 127, rh, (rh + 1) & 127, (rh + 2) & 127 };
    int cb0 = (2 * cw - 2) & 127;      // X[0] col
    int cb2 = (2 * cw) & 127;
    int cb4 = (2 * cw + 2) & 127;

    // per-row column sums: ce/co for c=2cw (idx 0) and c=2cw+1 (idx 1)
    float ce0[4], co0[4], ce1[4], co1[4];
    #pragma unroll
    for (int a = 0; a < 4; ++a) {
        const float* lr = lob + ri[a] * 128;
        float2 u0 = *(const float2*)(lr + cb0);   // X0 X1
        float2 u1 = *(const float2*)(lr + cb2);   // X2 X3
        float2 u2 = *(const float2*)(lr + cb4);   // X4 X5
        float X1 = u0.y, X2 = u1.x, X3 = u1.y, X4 = u2.x, X5 = u2.y;
        ce0[a] = g[1]*X1 + g[3]*X2 + g[5]*X3;
        co0[a] = g[0]*X1 + g[2]*X2 + g[4]*X3 + g[6]*X4;
        ce1[a] = g[1]*X2 + g[3]*X3 + g[5]*X4;
        co1[a] = g[0]*X2 + g[2]*X3 + g[4]*X4 + g[6]*X5;
    }
    // row combines: even h uses (g1,g3,g5) on a=0..2; odd h (g0,g2,g4,g6)
    float ae0 = g[1]*ce0[0] + g[3]*ce0[1] + g[5]*ce0[2];
    float ae1 = g[1]*co0[0] + g[3]*co0[1] + g[5]*co0[2];
    float ae2 = g[1]*ce1[0] + g[3]*ce1[1] + g[5]*ce1[2];
    float ae3 = g[1]*co1[0] + g[3]*co1[1] + g[5]*co1[2];
    float ao0 = g[0]*ce0[0] + g[2]*ce0[1] + g[4]*ce0[2] + g[6]*ce0[3];
    float ao1 = g[0]*co0[0] + g[2]*co0[1] + g[4]*co0[2] + g[6]*co0[3];
    float ao2 = g[0]*ce1[0] + g[2]*ce1[1] + g[4]*ce1[2] + g[6]*ce1[3];
    float ao3 = g[0]*co1[0] + g[2]*co1[1] + g[4]*co1[2] + g[6]*co1[3];

    size_t base = (size_t)bc * 65536 + (size_t)(2 * rh) * 256 + 4 * cw;
    float4 xe = *(const float4*)(x + base);
    float4 xo = *(const float4*)(x + base + 256);

    float* xsb = xs + (size_t)bc * 65536;
    int re = 2 * rh;
    // even row: sheared start even -> 2 float2
    int se = (4 * cw - re + 2) & 255;
    float* rowe = xsb + re * 256;
    *(float2*)(rowe + se)             = make_float2(xe.x - ae0, xe.y - ae1);
    *(float2*)(rowe + ((se + 2) & 255)) = make_float2(xe.z - ae2, xe.w - ae3);
    // odd row: sheared start odd -> 4 b32
    int so = (4 * cw - re + 1 + 256) & 255;   // 4cw-(2rh+1)+2
    float* rowo = xsb + (re + 1) * 256;
    rowo[so]             = xo.x - ao0;
    rowo[(so + 1) & 255] = xo.y - ao1;
    rowo[(so + 2) & 255] = xo.z - ao2;
    rowo[(so + 3) & 255] = xo.w - ao3;
}

// ---------------------------------------------------------------------------
// K34 fused, quarter-tiles: block = (bc, yidx, q). LDS tile = y[:,
// 2C0-4 .. 2C0+68) = 128x72 (36.9KB) -> 4 blocks/CU.
// Stage A: y[r][w] from sheared xs (row-independent aligned float4 window);
//   288 tasks (16 rowgroups x 18 4-col strips) over 256 threads.
// Stage B: out[2yidx+{0,1}, hh, cc] for cc in [C0,C0+32); sliding 22-row
//   window, T[p] = y[row][2cc-4+p], col 2cc-3+j -> p=j+1.
// ---------------------------------------------------------------------------
__global__ __launch_bounds__(256, 4) void k34_fused(
    const float* __restrict__ xs, const float* __restrict__ f0,
    const float* __restrict__ f1, float* __restrict__ out_hi)
{
    __shared__ float ylds[128 * 72];    // 36864 B
    int t = threadIdx.x;
    int q    = blockIdx.x & 3;
    int yidx = (blockIdx.x >> 2) & 1;
    int bc   = blockIdx.x >> 3;
    int C0 = 32 * q;
    const float* xsb = xs + (size_t)bc * 65536;
    const float* fy = yidx ? f1 : f0;

    // ---- Stage A ----
    for (int task = t; task < 288; task += 256) {
        int rg = task / 18;
        int s  = task - rg * 18;
        int r0 = rg * 8;
        int w0 = 2 * C0 - 4 + 4 * s;
        int c0 = (w0 - 4) & 255;

        float acc[8][4];
        #pragma unroll
        for (int lr = 0; lr < 8; ++lr)
            #pragma unroll
            for (int d = 0; d < 4; ++d) acc[lr][d] = 0.f;

        int base = 2 * r0 - 3;
        #pragma unroll
        for (int ro = 0; ro < 21; ++ro) {
            int row = (base + ro + 256) & 255;
            const float* rp = xsb + row * 256;
            float C[16];
            #pragma unroll
            for (int k = 0; k < 4; ++k) {
                float4 v = *(const float4*)(rp + ((c0 + 4 * k) & 255));
                C[4*k] = v.x; C[4*k+1] = v.y; C[4*k+2] = v.z; C[4*k+3] = v.w;
            }
            #pragma unroll
            for (int lr = 0; lr < 8; ++lr) {
                int i = ro - 2 * lr;
                if (i >= 0 && i <= 6) {
                    #pragma unroll
                    for (int j = 0; j < 7; ++j) {
                        float w = fy[i * 7 + j];
                        int mb = j - i + 6;
                        #pragma unroll
                        for (int d = 0; d < 4; ++d)
                            acc[lr][d] += w * C[d + mb];
                    }
                }
            }
        }
        #pragma unroll
        for (int lr = 0; lr < 8; ++lr) {
            *(float4*)(&ylds[(r0 + lr) * 72 + 4 * s]) =
                make_float4(acc[lr][0], acc[lr][1], acc[lr][2], acc[lr][3]);
        }
    }
    __syncthreads();

    // ---- Stage B ----
    {
        int ccl = t & 31;
        int lh  = t >> 5;                // hh = 16*lh + m
        int cc  = C0 + ccl;
        int rbase = (16 * lh + 2 * cc - 3 + 128) & 127;
        int cloc = 2 * ccl;              // local col of p=0 (y col 2cc-4)

        float s0[16], s1[16];
        #pragma unroll
        for (int m = 0; m < 16; ++m) { s0[m] = 0.f; s1[m] = 0.f; }

        #pragma unroll
        for (int RR = 0; RR < 22; ++RR) {
            const float* tr = &ylds[((rbase + RR) & 127) * 72 + cloc];
            float T[8];
            #pragma unroll
            for (int k = 0; k < 4; ++k) {
                float2 u = *(const float2*)(tr + 2 * k);
                T[2*k] = u.x; T[2*k+1] = u.y;
            }
            #pragma unroll
            for (int m = 0; m < 16; ++m) {
                int i = RR - m;
                if (i >= 0 && i <= 6) {
                    #pragma unroll
                    for (int j = 0; j < 7; ++j) {
                        s0[m] += f0[j * 7 + i] * T[j + 1];   // f0.T
                        s1[m] += f1[j * 7 + i] * T[j + 1];   // f1.T
                    }
                }
            }
        }
        #pragma unroll
        for (int m = 0; m < 16; ++m) {
            int hh = 16 * lh + m;
            size_t o = (size_t)bc * 65536 + (size_t)(2 * yidx) * 16384
                     + (size_t)hh * 128 + cc;
            out_hi[o]         = s0[m];
            out_hi[o + 16384] = s1[m];
        }
    }
}

// ---------------------------------------------------------------------------
extern "C" void kernel_launch(void* const* d_in, const int* in_sizes, int n_in,
                              void* d_out, int out_size, void* d_ws, size_t ws_size,
                              hipStream_t stream)
{
    const float* x  = (const float*)d_in[0];
    const float* h  = (const float*)d_in[1];
    const float* g  = (const float*)d_in[2];
    const float* f0 = (const float*)d_in[3];
    const float* f1 = (const float*)d_in[4];

    float* out   = (float*)d_out;
    float* xlo   = out;                 // 768*16384 floats
    float* hireg = out + 12582912;      // 768*65536: final subbands
    float* xsbuf = (float*)d_ws;        // sheared xhi, 768*65536 floats

    k1_lowpass<<<12288, 256, 0, stream>>>(x, h, xlo);
    k2_highpass<<<24576, 256, 0, stream>>>(x, g, xlo, xsbuf);
    k34_fused<<<6144, 256, 0, stream>>>(xsbuf, f0, f1, hireg);
}